// Round 12
// baseline (477.643 us; speedup 1.0000x reference)
//
#include <hip/hip_runtime.h>
#include <stdint.h>

#define T_STEPS 512
#define CELLS   4096            // 64*64
#define EPB     32              // envs per block (1 per lane, wave0 mirrored x2)
#define WPE     256             // packed world words per env (16 cells/word)
#define WPAD    258             // stride: word 0 and 257 = OOB sentinels (0), data at 1..256
#define ASTRIDE 132             // delta LDS stride: 128 words + pad (16B mult)
#define CHUNK   16              // steps per chunk (double-buffered flush)
#define NCHUNK  (T_STEPS / CHUNK)   // 32
#define SSTRIDE 34              // s-buf stride: 16 steps * 2 + 2 (even)
#define RSTRIDE 18              // r-buf stride: 16 + 2 (even)

// ---- Kernel 1: pack world (float walls+goals) to 2-bit codes in d_ws ----
// code: 2 = goal (g==10, priority), 1 = wall (w==1 && !goal), 0 = free
__device__ __forceinline__ uint32_t code4(float4 w, float4 g) {
    uint32_t b0 = (g.x == 10.0f) ? 2u : ((w.x == 1.0f) ? 1u : 0u);
    uint32_t b1 = (g.y == 10.0f) ? 2u : ((w.y == 1.0f) ? 1u : 0u);
    uint32_t b2 = (g.z == 10.0f) ? 2u : ((w.z == 1.0f) ? 1u : 0u);
    uint32_t b3 = (g.w == 10.0f) ? 2u : ((w.w == 1.0f) ? 1u : 0u);
    return b0 | (b1 << 2) | (b2 << 4) | (b3 << 6);   // 4 cells x 2 bits
}

__global__ __launch_bounds__(64) void pack_kernel(
    const float* __restrict__ world, uint32_t* __restrict__ packed)
{
    const int b = blockIdx.x;
    const int t = threadIdx.x;
    const float* wbase = world + (size_t)b * (2 * CELLS);
    const float* gbase = wbase + CELLS;
    #pragma unroll
    for (int h = 0; h < 4; ++h) {
        const int w  = h * 64 + t;     // word index, 16 cells per word
        const int c0 = w * 16;
        uint32_t word = 0;
        #pragma unroll
        for (int j = 0; j < 4; ++j) {
            float4 wf = *(const float4*)(wbase + c0 + 4 * j);
            float4 gf = *(const float4*)(gbase + c0 + 4 * j);
            word |= code4(wf, gf) << (8 * j);
        }
        packed[(size_t)b * WPE + w] = word;
    }
}

// action -> flat delta e = dr*64 + dc, stored as int8
__device__ __forceinline__ int actdelta(int a) {
    return (a == 1) ? -64 : ((a == 2) ? 64 : ((a == 3) ? -1 : ((a == 4) ? 1 : 0)));
}

// ---- Kernel 2: producer/consumer rollout, depth-4 lean speculation ----
__global__ __launch_bounds__(128) void rollout_kernel(
    const float* __restrict__ s0,
    const int*   __restrict__ act,
    const uint32_t* __restrict__ packed,
    float* __restrict__ out,
    int B)
{
    __shared__ uint32_t wlds[EPB * WPAD];         // 33024 B: biased 2-bit worlds
    __shared__ uint32_t alds[EPB * ASTRIDE];      // 16896 B: int8 step deltas
    __shared__ float    sbuf[2][EPB * SSTRIDE];   //  8704 B: dbuf s traj
    __shared__ float    rbuf[2][EPB * RSTRIDE];   //  4608 B: dbuf r traj
                                                  // total 63232 B

    const int tid = threadIdx.x;
    const int b0  = blockIdx.x * EPB;

    // ---- staging, 128 threads ----
    {   // worlds: data words at env*WPAD + 1 + w  (scalar writes: +1 unaligns b128)
        const uint4* gw = (const uint4*)(packed + (size_t)b0 * WPE);
        #pragma unroll 4
        for (int it = 0; it < 16; ++it) {
            const int idx = it * 128 + tid;
            const uint4 v = gw[idx];
            const int env  = idx >> 6;
            const int base = env * WPAD + 1 + (idx & 63) * 4;
            wlds[base]     = v.x;
            wlds[base + 1] = v.y;
            wlds[base + 2] = v.z;
            wlds[base + 3] = v.w;
        }
    }
    if (tid < 2 * EPB)   // sentinel words 0 and 257 of each env = free
        wlds[(tid >> 1) * WPAD + ((tid & 1) ? 257 : 0)] = 0u;
    {   // actions -> int8 deltas: 4096 words (128 per env)
        #pragma unroll 4
        for (int it = 0; it < 32; ++it) {
            const int widx = it * 128 + tid;
            const int env  = widx >> 7;
            const int w    = widx & 127;
            const int4 x = *(const int4*)(act + (size_t)(b0 + env) * T_STEPS + w * 4);
            const uint32_t dw = (uint32_t)(actdelta(x.x) & 255)
                              | ((uint32_t)(actdelta(x.y) & 255) << 8)
                              | ((uint32_t)(actdelta(x.z) & 255) << 16)
                              | ((uint32_t)(actdelta(x.w) & 255) << 24);
            alds[env * ASTRIDE + w] = dw;
        }
    }
    __syncthreads();

    float* const s_base = out;                                    // [B][513][2]
    float* const r_base = out + (size_t)B * (2 * (T_STEPS + 1));  // [B][513]

    if (tid < EPB) {   // t=0 outputs
        const float2 si = *(const float2*)(s0 + 2 * (size_t)(b0 + tid));
        *(float2*)(s_base + (size_t)(b0 + tid) * (2 * (T_STEPS + 1))) = si;
        r_base[(size_t)(b0 + tid) * (T_STEPS + 1)] = 0.0f;
    }

    // rollout state (wave 0 only; harmless for wave 1)
    const int e = tid & (EPB - 1);
    const float2 s = *(const float2*)(s0 + 2 * (size_t)(b0 + e));
    int c = (int)s.y;
    int p = ((int)s.x) * 64 + c;            // invariant: p == r*64 + c (exact)
    const uint32_t* myw = wlds + e * WPAD;
    const uint32_t* myd = alds + e * ASTRIDE;
    const int ft = tid - 64;                // flusher lane id

    // lean probe addressing (semantics identical to verified R3-R11 lookup):
    //   q in [-4096,4095]  -> data word 1 + ((q&4095)>>4)   (wrap handled by +256 term)
    //   q >= 4096          -> wb >= 257 -> clamped to sentinel 257 (free)
    //   q <= -4097         -> wb <= 0   -> clamped to sentinel 0   (free)
    //   sh = (q&15)*2 valid in all cases since 4096 % 16 == 0.
#define PROBE(S, W, SH)  do {                                              \
        const int q_  = p + (S);                                           \
        int wb_ = (q_ >> 4) + ((q_ >> 31) & 256) + 1;                      \
        wb_ = min(max(wb_, 0), 257);                                       \
        (W)  = myw[wb_];                                                   \
        (SH) = (q_ & 15) << 1;                                             \
    } while (0)

    for (int chunk = 0; chunk < NCHUNK; ++chunk) {
        if (tid < 64) {
            // ---- producer: 16 steps into buf[chunk&1], 4 per spec round ----
            float* sb = &sbuf[chunk & 1][e * SSTRIDE];
            float* rb = &rbuf[chunk & 1][e * RSTRIDE];
            const uint4 awv = *(const uint4*)(myd + chunk * 4);  // 16 steps, 1 wait
            const uint32_t aws[4] = {awv.x, awv.y, awv.z, awv.w};
            #pragma unroll
            for (int k = 0; k < 4; ++k) {
                const uint32_t aw = aws[k];
                const int e0 = (int)(aw << 24) >> 24;
                const int e1 = (int)(aw << 16) >> 24;
                const int e2 = (int)(aw << 8) >> 24;
                const int e3 = (int)aw >> 24;
                const int dc0 = e0 * (e0 & 1), dc1 = e1 * (e1 & 1);
                const int dc2 = e2 * (e2 & 1), dc3 = e3 * (e3 & 1);
                // subset sums (11 adds)
                const int s01 = e0 + e1;
                const int s12 = e1 + e2, s02 = e0 + e2, s012 = s01 + e2;
                const int s23 = e2 + e3, s13 = e1 + e3, s03 = e0 + e3;
                const int s123 = s12 + e3, s023 = s02 + e3, s013 = s01 + e3;
                const int s0123 = s012 + e3;
                // 15 probes, all issued before one (incremental) wait
                uint32_t W0, W1_0, W1_1, W2_00, W2_01, W2_10, W2_11;
                uint32_t W3_000, W3_001, W3_010, W3_011, W3_100, W3_101, W3_110, W3_111;
                int h0, h1_0, h1_1, h2_00, h2_01, h2_10, h2_11;
                int h3_000, h3_001, h3_010, h3_011, h3_100, h3_101, h3_110, h3_111;
                PROBE(e0,    W0,     h0);
                PROBE(e1,    W1_0,   h1_0);   PROBE(s01,   W1_1,   h1_1);
                PROBE(e2,    W2_00,  h2_00);  PROBE(s12,   W2_01,  h2_01);
                PROBE(s02,   W2_10,  h2_10);  PROBE(s012,  W2_11,  h2_11);
                PROBE(e3,    W3_000, h3_000); PROBE(s23,   W3_001, h3_001);
                PROBE(s13,   W3_010, h3_010); PROBE(s123,  W3_011, h3_011);
                PROBE(s03,   W3_100, h3_100); PROBE(s023,  W3_101, h3_101);
                PROBE(s013,  W3_110, h3_110); PROBE(s0123, W3_111, h3_111);

                const int ls = k * 4;
                // ---- step 0 ----
                const int v0 = (int)((W0 >> h0) & 3);
                const bool tk0 = (v0 != 1);
                const float rew0 = (v0 == 2) ? 1.0f : (tk0 ? -0.01f : -1.0f);
                const int m0 = (v0 & 1) - 1;          // -1 if taken, 0 if wall
                p += e0 & m0;  c += dc0 & m0;
                *(float2*)(&sb[2 * ls]) = make_float2((float)((p - c) >> 6), (float)c);
                // ---- step 1 ----
                const uint32_t W1 = tk0 ? W1_1 : W1_0;
                const int      H1 = tk0 ? h1_1 : h1_0;
                const int v1 = (int)((W1 >> H1) & 3);
                const bool tk1 = (v1 != 1);
                const float rew1 = (v1 == 2) ? 1.0f : (tk1 ? -0.01f : -1.0f);
                const int m1 = (v1 & 1) - 1;
                p += e1 & m1;  c += dc1 & m1;
                *(float2*)(&sb[2 * ls + 2]) = make_float2((float)((p - c) >> 6), (float)c);
                *(float2*)(&rb[ls]) = make_float2(rew0, rew1);
                // ---- step 2 ----  (select tree mirrors verified R6 structure)
                const uint32_t W2 = tk0 ? (tk1 ? W2_11 : W2_10)
                                        : (tk1 ? W2_01 : W2_00);
                const int      H2 = tk0 ? (tk1 ? h2_11 : h2_10)
                                        : (tk1 ? h2_01 : h2_00);
                const int v2 = (int)((W2 >> H2) & 3);
                const bool tk2 = (v2 != 1);
                const float rew2 = (v2 == 2) ? 1.0f : (tk2 ? -0.01f : -1.0f);
                const int m2 = (v2 & 1) - 1;
                p += e2 & m2;  c += dc2 & m2;
                *(float2*)(&sb[2 * ls + 4]) = make_float2((float)((p - c) >> 6), (float)c);
                // ---- step 3 ----
                const uint32_t W3 = tk0 ? (tk1 ? (tk2 ? W3_111 : W3_110)
                                               : (tk2 ? W3_101 : W3_100))
                                        : (tk1 ? (tk2 ? W3_011 : W3_010)
                                               : (tk2 ? W3_001 : W3_000));
                const int      H3 = tk0 ? (tk1 ? (tk2 ? h3_111 : h3_110)
                                               : (tk2 ? h3_101 : h3_100))
                                        : (tk1 ? (tk2 ? h3_011 : h3_010)
                                               : (tk2 ? h3_001 : h3_000));
                const int v3 = (int)((W3 >> H3) & 3);
                const bool tk3 = (v3 != 1);
                const float rew3 = (v3 == 2) ? 1.0f : (tk3 ? -0.01f : -1.0f);
                const int m3 = (v3 & 1) - 1;
                p += e3 & m3;  c += dc3 & m3;
                *(float2*)(&sb[2 * ls + 6]) = make_float2((float)((p - c) >> 6), (float)c);
                *(float2*)(&rb[ls + 2]) = make_float2(rew2, rew3);
            }
        } else if (chunk > 0) {
            // ---- consumer: flush chunk-1's buffers (coalesced) ----
            const int ch  = chunk - 1;
            const int buf = ch & 1;
            #pragma unroll 4
            for (int ee0 = 0; ee0 < EPB; ee0 += 2) {       // s: 32 floats/env
                const int ee = ee0 + (ft >> 5);
                const int j  = ft & 31;
                const float v = sbuf[buf][ee * SSTRIDE + j];
                s_base[(size_t)(b0 + ee) * (2 * (T_STEPS + 1)) + ch * 32 + 2 + j] = v;
            }
            #pragma unroll 4
            for (int ee0 = 0; ee0 < EPB; ee0 += 4) {       // r: 16 floats/env
                const int ee = ee0 + (ft >> 4);
                const int j  = ft & 15;
                const float v = rbuf[buf][ee * RSTRIDE + j];
                r_base[(size_t)(b0 + ee) * (T_STEPS + 1) + ch * 16 + 1 + j] = v;
            }
        }
        __syncthreads();
    }
    if (tid >= 64) {   // final flush: chunk NCHUNK-1
        const int ch  = NCHUNK - 1;
        const int buf = ch & 1;
        #pragma unroll 4
        for (int ee0 = 0; ee0 < EPB; ee0 += 2) {
            const int ee = ee0 + (ft >> 5);
            const int j  = ft & 31;
            const float v = sbuf[buf][ee * SSTRIDE + j];
            s_base[(size_t)(b0 + ee) * (2 * (T_STEPS + 1)) + ch * 32 + 2 + j] = v;
        }
        #pragma unroll 4
        for (int ee0 = 0; ee0 < EPB; ee0 += 4) {
            const int ee = ee0 + (ft >> 4);
            const int j  = ft & 15;
            const float v = rbuf[buf][ee * RSTRIDE + j];
            r_base[(size_t)(b0 + ee) * (T_STEPS + 1) + ch * 16 + 1 + j] = v;
        }
    }
#undef PROBE
}

extern "C" void kernel_launch(void* const* d_in, const int* in_sizes, int n_in,
                              void* d_out, int out_size, void* d_ws, size_t ws_size,
                              hipStream_t stream) {
    const float* s0    = (const float*)d_in[0];
    const int*   act   = (const int*)d_in[1];
    const float* world = (const float*)d_in[2];
    float*       out   = (float*)d_out;
    uint32_t*    packed = (uint32_t*)d_ws;     // needs B*256*4 = 8 MiB

    const int B = in_sizes[0] / 2;             // 8192

    pack_kernel<<<B, 64, 0, stream>>>(world, packed);
    rollout_kernel<<<B / EPB, 128, 0, stream>>>(s0, act, packed, out, B);
}

// Round 13
// 449.948 us; speedup vs baseline: 1.0616x; 1.0616x over previous
//
#include <hip/hip_runtime.h>
#include <stdint.h>

#define T_STEPS 512
#define CELLS   4096            // 64*64
#define EPB     16              // envs per block (4 per wave, lanes mirrored x16)
#define EPW     4               // envs per wave
#define WPE     256             // packed world words per env (16 cells/word)
#define WPAD    257             // world LDS stride; word 256 = OOB sentinel (0)
#define ASTRIDE 132             // delta LDS stride: 128 words + pad (16B mult)
#define CHUNK   16              // steps per chunk (self-flushed, single buffer)
#define NCHUNK  (T_STEPS / CHUNK)   // 32
#define KPC     (CHUNK / 4)         // 4 four-step k-iters per chunk
#define SSTRIDE 34              // s-buf stride: 16 steps * 2 + 2 (even)
#define RSTRIDE 18              // r-buf stride: 16 + 2 (even)

// ---- Kernel 1: pack world (float walls+goals) to 2-bit codes in d_ws ----
// code: 2 = goal (g==10, priority), 1 = wall (w==1 && !goal), 0 = free
__device__ __forceinline__ uint32_t code4(float4 w, float4 g) {
    uint32_t b0 = (g.x == 10.0f) ? 2u : ((w.x == 1.0f) ? 1u : 0u);
    uint32_t b1 = (g.y == 10.0f) ? 2u : ((w.y == 1.0f) ? 1u : 0u);
    uint32_t b2 = (g.z == 10.0f) ? 2u : ((w.z == 1.0f) ? 1u : 0u);
    uint32_t b3 = (g.w == 10.0f) ? 2u : ((w.w == 1.0f) ? 1u : 0u);
    return b0 | (b1 << 2) | (b2 << 4) | (b3 << 6);   // 4 cells x 2 bits
}

__global__ __launch_bounds__(64) void pack_kernel(
    const float* __restrict__ world, uint32_t* __restrict__ packed)
{
    const int b = blockIdx.x;
    const int t = threadIdx.x;
    const float* wbase = world + (size_t)b * (2 * CELLS);
    const float* gbase = wbase + CELLS;
    #pragma unroll
    for (int h = 0; h < 4; ++h) {
        const int w  = h * 64 + t;     // word index, 16 cells per word
        const int c0 = w * 16;
        uint32_t word = 0;
        #pragma unroll
        for (int j = 0; j < 4; ++j) {
            float4 wf = *(const float4*)(wbase + c0 + 4 * j);
            float4 gf = *(const float4*)(gbase + c0 + 4 * j);
            word |= code4(wf, gf) << (8 * j);
        }
        packed[(size_t)b * WPE + w] = word;
    }
}

// action -> flat delta e = dr*64 + dc, stored as int8
__device__ __forceinline__ int actdelta(int a) {
    return (a == 1) ? -64 : ((a == 2) ? 64 : ((a == 3) ? -1 : ((a == 4) ? 1 : 0)));
}

// ---- Kernel 2: rollout, 4 waves/block, 2 blocks/CU -> 2 waves per SIMD ----
// Each wave rolls 4 envs (lanes mirrored x16) and self-flushes -> no barriers
// in the main loop; two independent chains per SIMD fill each other's
// dependency bubbles.
__global__ __launch_bounds__(256, 2) void rollout_kernel(
    const float* __restrict__ s0,
    const int*   __restrict__ act,
    const uint32_t* __restrict__ packed,
    float* __restrict__ out,
    int B)
{
    __shared__ uint32_t wlds[EPB * WPAD];      // 16448 B: 2-bit worlds
    __shared__ uint32_t alds[EPB * ASTRIDE];   //  8448 B: int8 step deltas
    __shared__ float    sbuf[EPB * SSTRIDE];   //  2176 B: 16-step s traj
    __shared__ float    rbuf[EPB * RSTRIDE];   //  1152 B: 16-step r traj
                                               // total 28224 B -> 2 blocks/CU

    const int tid = threadIdx.x;
    const int b0  = blockIdx.x * EPB;

    // ---- staging, 256 threads ----
    {   // worlds: 1024 uint4 (64 per env)
        const uint4* gw = (const uint4*)(packed + (size_t)b0 * WPE);
        #pragma unroll
        for (int it = 0; it < 4; ++it) {
            const int idx = it * 256 + tid;
            const uint4 v = gw[idx];
            const int env  = idx >> 6;
            const int base = env * WPAD + (idx & 63) * 4;
            wlds[base]     = v.x;
            wlds[base + 1] = v.y;
            wlds[base + 2] = v.z;
            wlds[base + 3] = v.w;
        }
    }
    if (tid < EPB) wlds[tid * WPAD + WPE] = 0u;   // OOB sentinel word = free
    {   // actions -> int8 deltas: 2048 words (128 per env)
        #pragma unroll
        for (int it = 0; it < 8; ++it) {
            const int widx = it * 256 + tid;
            const int env  = widx >> 7;
            const int w    = widx & 127;
            const int4 x = *(const int4*)(act + (size_t)(b0 + env) * T_STEPS + w * 4);
            const uint32_t dw = (uint32_t)(actdelta(x.x) & 255)
                              | ((uint32_t)(actdelta(x.y) & 255) << 8)
                              | ((uint32_t)(actdelta(x.z) & 255) << 16)
                              | ((uint32_t)(actdelta(x.w) & 255) << 24);
            alds[env * ASTRIDE + w] = dw;
        }
    }
    __syncthreads();

    float* const s_base = out;                                    // [B][513][2]
    float* const r_base = out + (size_t)B * (2 * (T_STEPS + 1));  // [B][513]

    if (tid < EPB) {   // t=0 outputs
        const float2 si = *(const float2*)(s0 + 2 * (size_t)(b0 + tid));
        *(float2*)(s_base + (size_t)(b0 + tid) * (2 * (T_STEPS + 1))) = si;
        r_base[(size_t)(b0 + tid) * (T_STEPS + 1)] = 0.0f;
    }

    // rollout state: wave wv handles envs EPW*wv .. EPW*wv+3
    const int wv   = tid >> 6;
    const int lane = tid & 63;
    const int e    = EPW * wv + (lane & (EPW - 1));
    const float2 s = *(const float2*)(s0 + 2 * (size_t)(b0 + e));
    int c = (int)s.y;
    int p = ((int)s.x) * 64 + c;            // invariant: p == r*64 + c (exact)
    const uint32_t* myw = wlds + e * WPAD;
    const uint32_t* myd = alds + e * ASTRIDE;
    float* sb = &sbuf[e * SSTRIDE];
    float* rb = &rbuf[e * RSTRIDE];

    // semantics (verified R3-R12, absmax 0): idx in [-4096,-1] wraps (+4096,
    // single NumPy normalization); all other OOB -> fill(NaN) -> free cell.
    auto waddr = [](int q) -> int {
        const int w = (int)((((unsigned)q) >> 4) & 255u);   // (q & 4095) >> 4
        return ((unsigned)(q + CELLS) < 2u * CELLS) ? w : WPE;
    };

    for (int chunk = 0; chunk < NCHUNK; ++chunk) {
        // ---- produce 16 steps into this env's buffers ----
        const uint4 awv = *(const uint4*)(myd + chunk * 4);  // 16 steps, 1 wait
        const uint32_t aws[4] = {awv.x, awv.y, awv.z, awv.w};
        #pragma unroll
        for (int k = 0; k < KPC; ++k) {
            const uint32_t aw = aws[k];
            const int e0 = (int)(aw << 24) >> 24;
            const int e1 = (int)(aw << 16) >> 24;
            const int e2 = (int)(aw << 8) >> 24;
            const int e3 = (int)aw >> 24;
            const int es[4] = {e0, e1, e2, e3};
            #pragma unroll
            for (int jj = 0; jj < 2; ++jj) {    // two 2-step spec rounds
                const int ls = k * 4 + jj * 2;  // local step in chunk
                const int ea = es[2 * jj];
                const int eb = es[2 * jj + 1];
                const int dca = ea * (ea & 1);  // col part: ±1 -> ±1 else 0
                const int dcb = eb * (eb & 1);
                const int q0  = p + ea;
                const int q10 = p + eb;
                const int q11 = q0 + eb;
                const uint32_t w0  = myw[waddr(q0)];
                const uint32_t w10 = myw[waddr(q10)];
                const uint32_t w11 = myw[waddr(q11)];
                // resolve step t (identical to verified R8/R10/R11 logic)
                const int l0 = (int)((w0 >> ((q0 & 15) << 1)) & 3);
                const bool hw0 = (l0 == 1);
                const float rew0 = (l0 == 2) ? 1.0f : (hw0 ? -1.0f : -0.01f);
                const int p0 = hw0 ? p : q0;
                const int c0 = hw0 ? c : c + dca;
                // resolve step t+1 from matching speculative read
                const uint32_t W1 = hw0 ? w10 : w11;
                const int q1 = p0 + eb;
                const int l1 = (int)((W1 >> ((q1 & 15) << 1)) & 3);
                const bool hw1 = (l1 == 1);
                const float rew1 = (l1 == 2) ? 1.0f : (hw1 ? -1.0f : -0.01f);
                p = hw1 ? p0 : q1;
                c = hw1 ? c0 : c0 + dcb;
                const int r0i = (p0 - c0) >> 6;   // exact: p-c == 64*r
                const int rfi = (p - c) >> 6;
                *(float2*)(&sb[2 * ls])     = make_float2((float)r0i, (float)c0);
                *(float2*)(&sb[2 * ls + 2]) = make_float2((float)rfi, (float)c);
                *(float2*)(&rb[ls]) = make_float2(rew0, rew1);
            }
        }
        // ---- self-flush this wave's 4 envs (coalesced, no barrier) ----
        #pragma unroll
        for (int i = 0; i < 2; ++i) {            // s: 32 floats/env
            const int ee = EPW * wv + 2 * i + (lane >> 5);
            const int j  = lane & 31;
            const float v = sbuf[ee * SSTRIDE + j];
            s_base[(size_t)(b0 + ee) * (2 * (T_STEPS + 1)) + chunk * 32 + 2 + j] = v;
        }
        {                                        // r: 16 floats/env
            const int ee = EPW * wv + (lane >> 4);
            const int j  = lane & 15;
            const float v = rbuf[ee * RSTRIDE + j];
            r_base[(size_t)(b0 + ee) * (T_STEPS + 1) + chunk * 16 + 1 + j] = v;
        }
    }
}

extern "C" void kernel_launch(void* const* d_in, const int* in_sizes, int n_in,
                              void* d_out, int out_size, void* d_ws, size_t ws_size,
                              hipStream_t stream) {
    const float* s0    = (const float*)d_in[0];
    const int*   act   = (const int*)d_in[1];
    const float* world = (const float*)d_in[2];
    float*       out   = (float*)d_out;
    uint32_t*    packed = (uint32_t*)d_ws;     // needs B*256*4 = 8 MiB

    const int B = in_sizes[0] / 2;             // 8192

    pack_kernel<<<B, 64, 0, stream>>>(world, packed);
    rollout_kernel<<<B / EPB, 256, 0, stream>>>(s0, act, packed, out, B);
}

// Round 14
// 429.342 us; speedup vs baseline: 1.1125x; 1.0480x over previous
//
#include <hip/hip_runtime.h>
#include <stdint.h>

#define T_STEPS 512
#define CELLS   4096            // 64*64
#define EPB     32              // envs per block (1 per lane, wave0 mirrored x2)
#define WPE     256             // packed world words per env (16 cells/word)
#define WPAD    257             // world LDS stride; word 256 = OOB sentinel (0)
#define ASTRIDE 132             // delta LDS stride: 128 words + pad (16B mult)
#define CHUNK   16              // steps per chunk (double-buffered flush)
#define NCHUNK  (T_STEPS / CHUNK)   // 32
#define KPC     (CHUNK / 4)         // 4 four-step k-iters per chunk
#define TSTR    18              // packed traj stride: 16 words + 2 (even)

// ---- Kernel 1: pack world (float walls+goals) to 2-bit codes in d_ws ----
// code: 2 = goal (g==10, priority), 1 = wall (w==1 && !goal), 0 = free
__device__ __forceinline__ uint32_t code4(float4 w, float4 g) {
    uint32_t b0 = (g.x == 10.0f) ? 2u : ((w.x == 1.0f) ? 1u : 0u);
    uint32_t b1 = (g.y == 10.0f) ? 2u : ((w.y == 1.0f) ? 1u : 0u);
    uint32_t b2 = (g.z == 10.0f) ? 2u : ((w.z == 1.0f) ? 1u : 0u);
    uint32_t b3 = (g.w == 10.0f) ? 2u : ((w.w == 1.0f) ? 1u : 0u);
    return b0 | (b1 << 2) | (b2 << 4) | (b3 << 6);   // 4 cells x 2 bits
}

__global__ __launch_bounds__(64) void pack_kernel(
    const float* __restrict__ world, uint32_t* __restrict__ packed)
{
    const int b = blockIdx.x;
    const int t = threadIdx.x;
    const float* wbase = world + (size_t)b * (2 * CELLS);
    const float* gbase = wbase + CELLS;
    #pragma unroll
    for (int h = 0; h < 4; ++h) {
        const int w  = h * 64 + t;     // word index, 16 cells per word
        const int c0 = w * 16;
        uint32_t word = 0;
        #pragma unroll
        for (int j = 0; j < 4; ++j) {
            float4 wf = *(const float4*)(wbase + c0 + 4 * j);
            float4 gf = *(const float4*)(gbase + c0 + 4 * j);
            word |= code4(wf, gf) << (8 * j);
        }
        packed[(size_t)b * WPE + w] = word;
    }
}

// action -> flat delta e = dr*64 + dc, stored as int8
__device__ __forceinline__ int actdelta(int a) {
    return (a == 1) ? -64 : ((a == 2) ? 64 : ((a == 3) ? -1 : ((a == 4) ? 1 : 0)));
}

// ---- Kernel 2: producer/consumer rollout, packed trajectory words ----
// wave 0: rollout (env = tid&31, mirrored x2), writes 1 packed word/step
//         (half-exec: only lanes 0-31 write -> no same-address serialization)
// wave 1: unpacks + flushes previous chunk to global (coalesced), off-chain
__global__ __launch_bounds__(128) void rollout_kernel(
    const float* __restrict__ s0,
    const int*   __restrict__ act,
    const uint32_t* __restrict__ packed,
    float* __restrict__ out,
    int B)
{
    __shared__ uint32_t wlds[EPB * WPAD];        // 32896 B: 2-bit worlds
    __shared__ uint32_t alds[EPB * ASTRIDE];     // 16896 B: int8 step deltas
    __shared__ uint32_t tbuf[2][EPB * TSTR];     //  4608 B: packed traj dbuf
                                                 // total 54400 B

    const int tid = threadIdx.x;
    const int b0  = blockIdx.x * EPB;

    // ---- staging, 128 threads ----
    {   // worlds: 2048 uint4 loads (64 uint4 per env)
        const uint4* gw = (const uint4*)(packed + (size_t)b0 * WPE);
        #pragma unroll 4
        for (int it = 0; it < 16; ++it) {
            const int idx = it * 128 + tid;
            const uint4 v = gw[idx];
            const int env  = idx >> 6;
            const int base = env * WPAD + (idx & 63) * 4;
            wlds[base]     = v.x;
            wlds[base + 1] = v.y;
            wlds[base + 2] = v.z;
            wlds[base + 3] = v.w;
        }
    }
    if (tid < EPB) wlds[tid * WPAD + WPE] = 0u;   // OOB sentinel word = free
    {   // actions -> int8 deltas: 4096 words (128 per env)
        #pragma unroll 4
        for (int it = 0; it < 32; ++it) {
            const int widx = it * 128 + tid;
            const int env  = widx >> 7;
            const int w    = widx & 127;
            const int4 x = *(const int4*)(act + (size_t)(b0 + env) * T_STEPS + w * 4);
            const uint32_t dw = (uint32_t)(actdelta(x.x) & 255)
                              | ((uint32_t)(actdelta(x.y) & 255) << 8)
                              | ((uint32_t)(actdelta(x.z) & 255) << 16)
                              | ((uint32_t)(actdelta(x.w) & 255) << 24);
            alds[env * ASTRIDE + w] = dw;
        }
    }
    __syncthreads();

    float* const s_base = out;                                    // [B][513][2]
    float* const r_base = out + (size_t)B * (2 * (T_STEPS + 1));  // [B][513]

    if (tid < EPB) {   // t=0 outputs
        const float2 si = *(const float2*)(s0 + 2 * (size_t)(b0 + tid));
        *(float2*)(s_base + (size_t)(b0 + tid) * (2 * (T_STEPS + 1))) = si;
        r_base[(size_t)(b0 + tid) * (T_STEPS + 1)] = 0.0f;
    }

    // rollout state (wave 0 only; harmless for wave 1)
    const int e = tid & (EPB - 1);
    const float2 s = *(const float2*)(s0 + 2 * (size_t)(b0 + e));
    int c = (int)s.y;
    int p = ((int)s.x) * 64 + c;            // invariant: p == r*64 + c (exact)
    const uint32_t* myw = wlds + e * WPAD;
    const uint32_t* myd = alds + e * ASTRIDE;
    const int ft = tid - 64;                // flusher lane id

    // semantics (verified R3-R13, absmax 0): idx in [-4096,-1] wraps (+4096,
    // single NumPy normalization); all other OOB -> fill(NaN) -> free cell.
    auto waddr = [](int q) -> int {
        const int w = (int)((((unsigned)q) >> 4) & 255u);   // (q & 4095) >> 4
        return ((unsigned)(q + CELLS) < 2u * CELLS) ? w : WPE;
    };

    for (int chunk = 0; chunk < NCHUNK; ++chunk) {
        if (tid < 64) {
            // ---- producer: 16 steps into tbuf[chunk&1], packed ----
            uint32_t* tb = &tbuf[chunk & 1][e * TSTR];
            const uint4 awv = *(const uint4*)(myd + chunk * 4);  // 16 steps, 1 wait
            const uint32_t aws[4] = {awv.x, awv.y, awv.z, awv.w};
            #pragma unroll
            for (int k = 0; k < KPC; ++k) {
                const uint32_t aw = aws[k];
                const int e0 = (int)(aw << 24) >> 24;
                const int e1 = (int)(aw << 16) >> 24;
                const int e2 = (int)(aw << 8) >> 24;
                const int e3 = (int)aw >> 24;
                const int es[4] = {e0, e1, e2, e3};
                #pragma unroll
                for (int jj = 0; jj < 2; ++jj) {    // two 2-step spec rounds
                    const int ls = k * 4 + jj * 2;  // local step in chunk
                    const int ea = es[2 * jj];
                    const int eb = es[2 * jj + 1];
                    const int dca = ea * (ea & 1);  // col part: ±1 -> ±1 else 0
                    const int dcb = eb * (eb & 1);
                    const int q0  = p + ea;
                    const int q10 = p + eb;
                    const int q11 = q0 + eb;
                    const uint32_t w0  = myw[waddr(q0)];
                    const uint32_t w10 = myw[waddr(q10)];
                    const uint32_t w11 = myw[waddr(q11)];
                    // resolve step t (identical to verified R8/R10/R11 logic)
                    const int l0 = (int)((w0 >> ((q0 & 15) << 1)) & 3);
                    const bool hw0 = (l0 == 1);
                    const int p0 = hw0 ? p : q0;
                    const int c0 = hw0 ? c : c + dca;
                    // resolve step t+1 from matching speculative read
                    const uint32_t W1 = hw0 ? w10 : w11;
                    const int q1 = p0 + eb;
                    const int l1 = (int)((W1 >> ((q1 & 15) << 1)) & 3);
                    const bool hw1 = (l1 == 1);
                    p = hw1 ? p0 : q1;
                    c = hw1 ? c0 : c0 + dcb;
                    // packed: bits[31:14]=p (18b signed), [13:2]=c (12b), [1:0]=cell
                    const uint32_t pk0 = ((uint32_t)p0 << 14)
                                       | (((uint32_t)c0 & 0xFFFu) << 2) | (uint32_t)l0;
                    const uint32_t pk1 = ((uint32_t)p << 14)
                                       | (((uint32_t)c & 0xFFFu) << 2) | (uint32_t)l1;
                    if (tid < 32)   // mirrored lanes skip: avoid same-addr serialization
                        *(uint2*)(&tb[ls]) = make_uint2(pk0, pk1);
                }
            }
        } else if (chunk > 0) {
            // ---- consumer: unpack + flush chunk-1 (coalesced) ----
            const int ch  = chunk - 1;
            const int buf = ch & 1;
            #pragma unroll 4
            for (int ee0 = 0; ee0 < EPB; ee0 += 2) {       // s: 32 floats/env
                const int ee = ee0 + (ft >> 5);
                const int j  = ft & 31;
                const uint32_t pk = tbuf[buf][ee * TSTR + (j >> 1)];
                const int pp = ((int)pk) >> 14;
                const int cc = ((int)(pk << 18)) >> 20;
                const float v = (j & 1) ? (float)cc : (float)((pp - cc) >> 6);
                s_base[(size_t)(b0 + ee) * (2 * (T_STEPS + 1)) + ch * 32 + 2 + j] = v;
            }
            #pragma unroll 4
            for (int ee0 = 0; ee0 < EPB; ee0 += 4) {       // r: 16 floats/env
                const int ee = ee0 + (ft >> 4);
                const int j  = ft & 15;
                const int v  = (int)(tbuf[buf][ee * TSTR + j] & 3u);
                const float rew = (v == 2) ? 1.0f : ((v == 1) ? -1.0f : -0.01f);
                r_base[(size_t)(b0 + ee) * (T_STEPS + 1) + ch * 16 + 1 + j] = rew;
            }
        }
        __syncthreads();
    }
    if (tid >= 64) {   // final flush: chunk NCHUNK-1
        const int ch  = NCHUNK - 1;
        const int buf = ch & 1;
        #pragma unroll 4
        for (int ee0 = 0; ee0 < EPB; ee0 += 2) {
            const int ee = ee0 + (ft >> 5);
            const int j  = ft & 31;
            const uint32_t pk = tbuf[buf][ee * TSTR + (j >> 1)];
            const int pp = ((int)pk) >> 14;
            const int cc = ((int)(pk << 18)) >> 20;
            const float v = (j & 1) ? (float)cc : (float)((pp - cc) >> 6);
            s_base[(size_t)(b0 + ee) * (2 * (T_STEPS + 1)) + ch * 32 + 2 + j] = v;
        }
        #pragma unroll 4
        for (int ee0 = 0; ee0 < EPB; ee0 += 4) {
            const int ee = ee0 + (ft >> 4);
            const int j  = ft & 15;
            const int v  = (int)(tbuf[buf][ee * TSTR + j] & 3u);
            const float rew = (v == 2) ? 1.0f : ((v == 1) ? -1.0f : -0.01f);
            r_base[(size_t)(b0 + ee) * (T_STEPS + 1) + ch * 16 + 1 + j] = rew;
        }
    }
}

extern "C" void kernel_launch(void* const* d_in, const int* in_sizes, int n_in,
                              void* d_out, int out_size, void* d_ws, size_t ws_size,
                              hipStream_t stream) {
    const float* s0    = (const float*)d_in[0];
    const int*   act   = (const int*)d_in[1];
    const float* world = (const float*)d_in[2];
    float*       out   = (float*)d_out;
    uint32_t*    packed = (uint32_t*)d_ws;     // needs B*256*4 = 8 MiB

    const int B = in_sizes[0] / 2;             // 8192

    pack_kernel<<<B, 64, 0, stream>>>(world, packed);
    rollout_kernel<<<B / EPB, 128, 0, stream>>>(s0, act, packed, out, B);
}